// Round 4
// baseline (1094.565 us; speedup 1.0000x reference)
//
#include <hip/hip_runtime.h>
#include <hip/hip_bf16.h>
#include <math.h>

using bf16 = __hip_bfloat16;

typedef __bf16 bf16x8 __attribute__((ext_vector_type(8)));
typedef float f32x4 __attribute__((ext_vector_type(4)));

__device__ __forceinline__ float bf2f(bf16 v) { return __bfloat162float(v); }
__device__ __forceinline__ bf16 f2bf(float v) { return __float2bfloat16(v); }
__device__ __forceinline__ float bits2f(unsigned short h) {
    union { unsigned u; float f; } x; x.u = ((unsigned)h) << 16; return x.f;
}
__device__ __forceinline__ float nz(float v) { return (v == v) ? v : 0.0f; }

// Problem constants
#define CDIM 192
#define NHEADS 6
#define ROWS 131072        // 8 * 128 * 128
#define HIDDEN 768

// ---------------------------------------------------------------------------
// K1: LN1 + cyclic shift (-4,-4) + window partition. One wave per token.
// fp32 in -> bf16 out (xw).
// ---------------------------------------------------------------------------
__global__ __launch_bounds__(256) void k_ln1_part(const float* __restrict__ x,
                                                  const float* __restrict__ g,
                                                  const float* __restrict__ bta,
                                                  bf16* __restrict__ xw) {
    int tid = threadIdx.x;
    int lane = tid & 63;
    int t = (blockIdx.x << 2) + (tid >> 6);   // chunk-local token id
    int w = t >> 6, n = t & 63;
    int bb = w >> 8, wy = (w >> 4) & 15, wx = w & 15;
    int iy = n >> 3, ix = n & 7;
    int hs = (wy * 8 + iy + 4) & 127;
    int vs = (wx * 8 + ix + 4) & 127;
    const float* xr = x + ((size_t)bb * 16384 + (size_t)hs * 128 + vs) * CDIM;
    float v0 = nz(xr[lane]);
    float v1 = nz(xr[lane + 64]);
    float v2 = nz(xr[lane + 128]);
    float s = v0 + v1 + v2;
    float q = v0 * v0 + v1 * v1 + v2 * v2;
#pragma unroll
    for (int o = 32; o > 0; o >>= 1) { s += __shfl_xor(s, o); q += __shfl_xor(q, o); }
    float mean = s * (1.0f / 192.0f);
    float var = q * (1.0f / 192.0f) - mean * mean;
    float rs = rsqrtf(var + 1e-5f);
    bf16* orow = xw + (size_t)t * CDIM;
    orow[lane]       = f2bf((v0 - mean) * rs * g[lane]       + bta[lane]);
    orow[lane + 64]  = f2bf((v1 - mean) * rs * g[lane + 64]  + bta[lane + 64]);
    orow[lane + 128] = f2bf((v2 - mean) * rs * g[lane + 128] + bta[lane + 128]);
}

// ---------------------------------------------------------------------------
// Weight transpose + fp32->bf16: in[K,N] f32 -> out[N,K] bf16
// ---------------------------------------------------------------------------
__global__ void k_transpose(const float* __restrict__ in, bf16* __restrict__ out, int K, int N) {
    int i = blockIdx.x * 256 + threadIdx.x;
    if (i < K * N) {
        int k = i / N, n = i - k * N;
        out[(size_t)n * K + k] = f2bf(in[i]);
    }
}

// ---------------------------------------------------------------------------
// Dynamic position-bias MLP (all fp32): 225 rows, 3 stages of LN->ReLU->W.
// ---------------------------------------------------------------------------
__global__ __launch_bounds__(256) void k_posmlp(
    const float* __restrict__ pp_w, const float* __restrict__ pp_b,
    const float* __restrict__ p1_g, const float* __restrict__ p1_b,
    const float* __restrict__ p1_w, const float* __restrict__ p1_bias,
    const float* __restrict__ p2_g, const float* __restrict__ p2_b,
    const float* __restrict__ p2_w, const float* __restrict__ p2_bias,
    const float* __restrict__ p3_g, const float* __restrict__ p3_b,
    const float* __restrict__ p3_w, const float* __restrict__ p3_bias,
    float* __restrict__ pos) {
    int i = threadIdx.x;
    if (i >= 225) return;
    float bh = (float)(i / 15 - 7), bw = (float)(i % 15 - 7);
    float v[12], u[12];
#pragma unroll
    for (int j = 0; j < 12; j++)
        v[j] = bh * pp_w[j] + bw * pp_w[12 + j] + pp_b[j];

    auto stage = [&](const float* gg, const float* bb2, const float* Wm, const float* bs, int OD) {
        float mean = 0.f;
        for (int j = 0; j < 12; j++) mean += v[j];
        mean *= (1.0f / 12.0f);
        float var = 0.f;
        for (int j = 0; j < 12; j++) { float d = v[j] - mean; var += d * d; }
        var *= (1.0f / 12.0f);
        float rs = rsqrtf(var + 1e-5f);
        for (int j = 0; j < 12; j++)
            u[j] = fmaxf((v[j] - mean) * rs * gg[j] + bb2[j], 0.0f);
        for (int o = 0; o < OD; o++) {
            float a = bs[o];
            for (int j = 0; j < 12; j++) a += u[j] * Wm[j * OD + o];
            v[o] = a;
        }
    };
    stage(p1_g, p1_b, p1_w, p1_bias, 12);
    stage(p2_g, p2_b, p2_w, p2_bias, 12);
    stage(p3_g, p3_b, p3_w, p3_bias, 6);
    for (int h = 0; h < 6; h++) pos[i * 6 + h] = v[h];
}

// ---------------------------------------------------------------------------
// MFMA GEMM: C[M,N] = act(A[M,K] @ W[K,N] + bias) (+ residual in C)
// A,Bt bf16; bias fp32; OutT = bf16 or float. Tile 128x64, BK=64, 4 waves.
// ---------------------------------------------------------------------------
template <int ACT, int RESID, typename OutT>
__global__ __launch_bounds__(256) void k_gemm(const bf16* __restrict__ A,
                                              const bf16* __restrict__ Bt,
                                              const float* __restrict__ bias,
                                              OutT* __restrict__ Cd,
                                              int M, int N, int K) {
    constexpr int BM = 128, BN = 64, BK = 64, LDT = 72;
    __shared__ __align__(16) unsigned short As[BM * LDT];
    __shared__ __align__(16) unsigned short Bs[BN * LDT];
    int tid = threadIdx.x;
    int wave = tid >> 6, lane = tid & 63;
    int lm = lane & 15, quad = lane >> 4;
    int m0 = blockIdx.x * BM, n0 = blockIdx.y * BN;

    f32x4 acc[2][4] = {};

    for (int k0 = 0; k0 < K; k0 += BK) {
#pragma unroll
        for (int i = 0; i < 4; i++) {
            int c = tid + i * 256;
            int row = c >> 3, col = (c & 7) << 3;
            *(uint4*)&As[row * LDT + col] =
                *(const uint4*)&A[(size_t)(m0 + row) * K + k0 + col];
        }
#pragma unroll
        for (int i = 0; i < 2; i++) {
            int c = tid + i * 256;
            int row = c >> 3, col = (c & 7) << 3;
            *(uint4*)&Bs[row * LDT + col] =
                *(const uint4*)&Bt[(size_t)(n0 + row) * K + k0 + col];
        }
        __syncthreads();
#pragma unroll
        for (int ks = 0; ks < BK; ks += 32) {
            bf16x8 af[2], bfr[4];
#pragma unroll
            for (int im = 0; im < 2; im++)
                af[im] = *(const bf16x8*)&As[(wave * 32 + im * 16 + lm) * LDT + ks + quad * 8];
#pragma unroll
            for (int in = 0; in < 4; in++)
                bfr[in] = *(const bf16x8*)&Bs[(in * 16 + lm) * LDT + ks + quad * 8];
#pragma unroll
            for (int im = 0; im < 2; im++)
#pragma unroll
                for (int in = 0; in < 4; in++)
                    acc[im][in] = __builtin_amdgcn_mfma_f32_16x16x32_bf16(
                        af[im], bfr[in], acc[im][in], 0, 0, 0);
        }
        __syncthreads();
    }

    // epilogue: C/D layout col=lane&15, row=quad*4+reg
#pragma unroll
    for (int im = 0; im < 2; im++) {
        int rbase = m0 + wave * 32 + im * 16 + quad * 4;
#pragma unroll
        for (int in = 0; in < 4; in++) {
            int cg = n0 + in * 16 + lm;
            float bv = bias[cg];
#pragma unroll
            for (int r = 0; r < 4; r++) {
                float v = acc[im][in][r] + bv;
                if (ACT == 1) v = 0.5f * v * (1.0f + erff(v * 0.70710678118654752f));
                size_t o = (size_t)(rbase + r) * N + cg;
                if (RESID) v += (float)Cd[o];
                Cd[o] = (OutT)v;
            }
        }
    }
}

// ---------------------------------------------------------------------------
// Attention per (window, head). qkv bf16 in, bf16 out.
// ---------------------------------------------------------------------------
__global__ __launch_bounds__(256) void k_attn(const bf16* __restrict__ qkv,
                                              const float* __restrict__ pos,
                                              bf16* __restrict__ outp) {
    __shared__ float qs[64 * 33], ksm[64 * 33], vsm[64 * 33], ps[64 * 65];
    int w = blockIdx.x, head = blockIdx.y;
    int tid = threadIdx.x;
    int wy = (w >> 4) & 15, wx = w & 15;
    const float scale = 0.17677669529663687f;  // 32^-0.5

    {
        int n = tid >> 2, d0 = (tid & 3) << 3;
        const unsigned short* base =
            (const unsigned short*)qkv + (size_t)(w * 64 + n) * 576 + head * 32 + d0;
        uint4 uq = *(const uint4*)(base);
        uint4 uk = *(const uint4*)(base + 192);
        uint4 uv = *(const uint4*)(base + 384);
        const unsigned short* pq = (const unsigned short*)&uq;
        const unsigned short* pk = (const unsigned short*)&uk;
        const unsigned short* pv = (const unsigned short*)&uv;
#pragma unroll
        for (int j = 0; j < 8; j++) {
            qs[n * 33 + d0 + j] = bits2f(pq[j]) * scale;
            ksm[n * 33 + d0 + j] = bits2f(pk[j]);
            vsm[n * 33 + d0 + j] = bits2f(pv[j]);
        }
    }
    __syncthreads();

    int m = tid & 63, wv = tid >> 6;
    int iym = m >> 3, ixm = m & 7;
    int hm = wy * 8 + iym, wm = wx * 8 + ixm;
    int ridm = (hm < 120 ? 0 : (hm < 124 ? 1 : 2)) * 3 + (wm < 120 ? 0 : (wm < 124 ? 1 : 2));
    bool edge = (wy == 15) || (wx == 15);
#pragma unroll 1
    for (int it = 0; it < 16; it++) {
        int n = wv * 16 + it;
        float s = 0.f;
#pragma unroll
        for (int d = 0; d < 32; d++) s += qs[n * 33 + d] * ksm[m * 33 + d];
        int iyn = n >> 3, ixn = n & 7;
        s += pos[((iyn - iym + 7) * 15 + (ixn - ixm + 7)) * 6 + head];
        if (edge) {
            int hn = wy * 8 + iyn, wn = wx * 8 + ixn;
            int ridn = (hn < 120 ? 0 : (hn < 124 ? 1 : 2)) * 3 + (wn < 120 ? 0 : (wn < 124 ? 1 : 2));
            if (ridn != ridm) s -= 100.0f;
        }
        float mx = s;
#pragma unroll
        for (int o = 32; o > 0; o >>= 1) mx = fmaxf(mx, __shfl_xor(mx, o));
        float e = expf(s - mx);
        float sum = e;
#pragma unroll
        for (int o = 32; o > 0; o >>= 1) sum += __shfl_xor(sum, o);
        ps[n * 65 + m] = e / sum;
    }
    __syncthreads();

    int d = tid & 31, half = tid >> 5;
#pragma unroll 1
    for (int it = 0; it < 8; it++) {
        int n = half * 8 + it;
        float o = 0.f;
#pragma unroll
        for (int mm = 0; mm < 64; mm++) o += ps[n * 65 + mm] * vsm[mm * 33 + d];
        outp[(size_t)(w * 64 + n) * 192 + head * 32 + d] = f2bf(o);
    }
}

// ---------------------------------------------------------------------------
// K5: window reverse + shift back (+4,+4) + residual -> y (fp32 d_out),
// then LN2(y) -> h2 (bf16).
// ---------------------------------------------------------------------------
__global__ __launch_bounds__(256) void k_resid_ln2(const float* __restrict__ x,
                                                   const bf16* __restrict__ proj,
                                                   const float* __restrict__ g,
                                                   const float* __restrict__ bta,
                                                   float* __restrict__ yout,
                                                   bf16* __restrict__ h2) {
    int tid = threadIdx.x, lane = tid & 63;
    int t = (blockIdx.x << 2) + (tid >> 6);
    int bb = t >> 14, l = t & 16383;
    int h = l >> 7, ww = l & 127;
    int hr = (h + 124) & 127, wr = (ww + 124) & 127;  // (h-4) mod 128
    int win = bb * 256 + (hr >> 3) * 16 + (wr >> 3);
    int n = ((hr & 7) << 3) + (wr & 7);
    const float* xr = x + (size_t)t * CDIM;
    const bf16* pr = proj + ((size_t)win * 64 + n) * CDIM;
    float v0 = nz(xr[lane])       + bf2f(pr[lane]);
    float v1 = nz(xr[lane + 64])  + bf2f(pr[lane + 64]);
    float v2 = nz(xr[lane + 128]) + bf2f(pr[lane + 128]);
    float* yr = yout + (size_t)t * CDIM;
    yr[lane]       = v0;
    yr[lane + 64]  = v1;
    yr[lane + 128] = v2;
    float s = v0 + v1 + v2;
    float q = v0 * v0 + v1 * v1 + v2 * v2;
#pragma unroll
    for (int o = 32; o > 0; o >>= 1) { s += __shfl_xor(s, o); q += __shfl_xor(q, o); }
    float mean = s * (1.0f / 192.0f);
    float var = q * (1.0f / 192.0f) - mean * mean;
    float rs = rsqrtf(var + 1e-5f);
    bf16* hr2 = h2 + (size_t)t * CDIM;
    hr2[lane]       = f2bf((v0 - mean) * rs * g[lane]       + bta[lane]);
    hr2[lane + 64]  = f2bf((v1 - mean) * rs * g[lane + 64]  + bta[lane + 64]);
    hr2[lane + 128] = f2bf((v2 - mean) * rs * g[lane + 128] + bta[lane + 128]);
}

// ---------------------------------------------------------------------------
extern "C" void kernel_launch(void* const* d_in, const int* in_sizes, int n_in,
                              void* d_out, int out_size, void* d_ws, size_t ws_size,
                              hipStream_t stream) {
    (void)in_sizes; (void)n_in; (void)out_size;
    const float* x      = (const float*)d_in[0];
    const float* n1_g   = (const float*)d_in[4];
    const float* n1_b   = (const float*)d_in[5];
    const float* qkv_w  = (const float*)d_in[6];
    const float* qkv_b  = (const float*)d_in[7];
    const float* proj_w = (const float*)d_in[8];
    const float* proj_b = (const float*)d_in[9];
    const float* pp_w   = (const float*)d_in[10];
    const float* pp_b   = (const float*)d_in[11];
    const float* p1_g   = (const float*)d_in[12];
    const float* p1_b   = (const float*)d_in[13];
    const float* p1_w   = (const float*)d_in[14];
    const float* p1_bias= (const float*)d_in[15];
    const float* p2_g   = (const float*)d_in[16];
    const float* p2_b   = (const float*)d_in[17];
    const float* p2_w   = (const float*)d_in[18];
    const float* p2_bias= (const float*)d_in[19];
    const float* p3_g   = (const float*)d_in[20];
    const float* p3_b   = (const float*)d_in[21];
    const float* p3_w   = (const float*)d_in[22];
    const float* p3_bias= (const float*)d_in[23];
    const float* n2_g   = (const float*)d_in[24];
    const float* n2_b   = (const float*)d_in[25];
    const float* fc1_w  = (const float*)d_in[26];
    const float* fc1_b  = (const float*)d_in[27];
    const float* fc2_w  = (const float*)d_in[28];
    const float* fc2_b  = (const float*)d_in[29];

    char* ws = (char*)d_ws;
    size_t off = 0;
    auto alloc = [&](size_t bytes) -> char* {
        char* p = ws + off;
        off += (bytes + 255) & ~(size_t)255;
        return p;
    };
    // bf16 weight copies + pos (~0.9 MB)
    bf16* qkvwT  = (bf16*)alloc((size_t)CDIM * 576 * 2);
    bf16* projwT = (bf16*)alloc((size_t)CDIM * CDIM * 2);
    bf16* fc1wT  = (bf16*)alloc((size_t)CDIM * HIDDEN * 2);
    bf16* fc2wT  = (bf16*)alloc((size_t)HIDDEN * CDIM * 2);
    float* pos   = (float*)alloc(225 * 6 * 4);

    const size_t flatNeed = (size_t)ROWS * CDIM * 2 + (size_t)ROWS * HIDDEN * 2 + (1u << 20);
    const bool flat = (ws_size > off) && ((ws_size - off) >= flatNeed);
    const int NCH = flat ? 1 : 8;
    const int NIMG = flat ? 8 : 1;
    const size_t R = (size_t)16384 * NIMG;   // rows per chunk

    bf16 *xw_b, *qkv_buf, *attn_b, *proj_buf, *h2_b, *fc1_buf;
    if (flat) {
        bf16* region0 = (bf16*)alloc((size_t)ROWS * CDIM * 2);
        bf16* region1 = (bf16*)alloc((size_t)ROWS * HIDDEN * 2);
        xw_b = attn_b = h2_b = region0;            // sequential lifetimes
        qkv_buf  = region1;
        proj_buf = region1 + (size_t)ROWS * 576;
        fc1_buf  = region1;                        // qkv/proj dead by then
    } else {
        xw_b     = (bf16*)alloc(R * CDIM * 2);
        qkv_buf  = (bf16*)alloc(R * 576 * 2);
        attn_b   = (bf16*)alloc(R * CDIM * 2);
        proj_buf = (bf16*)alloc(R * CDIM * 2);
        h2_b     = (bf16*)alloc(R * CDIM * 2);
        fc1_buf  = (bf16*)alloc(R * HIDDEN * 2);
    }
    float* yout = (float*)d_out;

    // prep (tiny)
    k_transpose<<<(CDIM * 576 + 255) / 256, 256, 0, stream>>>(qkv_w, qkvwT, CDIM, 576);
    k_transpose<<<(CDIM * CDIM + 255) / 256, 256, 0, stream>>>(proj_w, projwT, CDIM, CDIM);
    k_transpose<<<(CDIM * HIDDEN + 255) / 256, 256, 0, stream>>>(fc1_w, fc1wT, CDIM, HIDDEN);
    k_transpose<<<(HIDDEN * CDIM + 255) / 256, 256, 0, stream>>>(fc2_w, fc2wT, HIDDEN, CDIM);
    k_posmlp<<<1, 256, 0, stream>>>(pp_w, pp_b, p1_g, p1_b, p1_w, p1_bias,
                                    p2_g, p2_b, p2_w, p2_bias,
                                    p3_g, p3_b, p3_w, p3_bias, pos);

    for (int c = 0; c < NCH; ++c) {
        const float* x_c = x + (size_t)c * 16384 * CDIM;
        float* y_c = yout + (size_t)c * 16384 * CDIM;

        k_ln1_part<<<(int)(R / 4), 256, 0, stream>>>(x_c, n1_g, n1_b, xw_b);

        k_gemm<0, 0, bf16><<<dim3((int)(R / 128), 576 / 64), 256, 0, stream>>>(
            xw_b, qkvwT, qkv_b, qkv_buf, (int)R, 576, CDIM);

        k_attn<<<dim3((int)(R / 64), NHEADS), 256, 0, stream>>>(qkv_buf, pos, attn_b);

        k_gemm<0, 0, bf16><<<dim3((int)(R / 128), CDIM / 64), 256, 0, stream>>>(
            attn_b, projwT, proj_b, proj_buf, (int)R, CDIM, CDIM);

        k_resid_ln2<<<(int)(R / 4), 256, 0, stream>>>(x_c, proj_buf, n2_g, n2_b, y_c, h2_b);

        k_gemm<1, 0, bf16><<<dim3((int)(R / 128), HIDDEN / 64), 256, 0, stream>>>(
            h2_b, fc1wT, fc1_b, fc1_buf, (int)R, HIDDEN, CDIM);

        k_gemm<0, 1, float><<<dim3((int)(R / 128), CDIM / 64), 256, 0, stream>>>(
            fc1_buf, fc2wT, fc2_b, y_c, (int)R, CDIM, HIDDEN);
    }
}

// Round 5
// 821.971 us; speedup vs baseline: 1.3316x; 1.3316x over previous
//
#include <hip/hip_runtime.h>
#include <hip/hip_bf16.h>
#include <math.h>

using bf16 = __hip_bfloat16;

typedef __bf16 bf16x8 __attribute__((ext_vector_type(8)));
typedef float f32x4 __attribute__((ext_vector_type(4)));

__device__ __forceinline__ float bf2f(bf16 v) { return __bfloat162float(v); }
__device__ __forceinline__ bf16 f2bf(float v) { return __float2bfloat16(v); }
__device__ __forceinline__ float nz(float v) { return (v == v) ? v : 0.0f; }

// Problem constants
#define CDIM 192
#define NHEADS 6
#define ROWS 131072        // 8 * 128 * 128
#define HIDDEN 768

// ---------------------------------------------------------------------------
// K1: LN1 + cyclic shift (-4,-4) + window partition. One wave per token.
// fp32 in -> bf16 out (xw).
// ---------------------------------------------------------------------------
__global__ __launch_bounds__(256) void k_ln1_part(const float* __restrict__ x,
                                                  const float* __restrict__ g,
                                                  const float* __restrict__ bta,
                                                  bf16* __restrict__ xw) {
    int tid = threadIdx.x;
    int lane = tid & 63;
    int t = (blockIdx.x << 2) + (tid >> 6);   // chunk-local token id
    int w = t >> 6, n = t & 63;
    int bb = w >> 8, wy = (w >> 4) & 15, wx = w & 15;
    int iy = n >> 3, ix = n & 7;
    int hs = (wy * 8 + iy + 4) & 127;
    int vs = (wx * 8 + ix + 4) & 127;
    const float* xr = x + ((size_t)bb * 16384 + (size_t)hs * 128 + vs) * CDIM;
    float v0 = nz(xr[lane]);
    float v1 = nz(xr[lane + 64]);
    float v2 = nz(xr[lane + 128]);
    float s = v0 + v1 + v2;
    float q = v0 * v0 + v1 * v1 + v2 * v2;
#pragma unroll
    for (int o = 32; o > 0; o >>= 1) { s += __shfl_xor(s, o); q += __shfl_xor(q, o); }
    float mean = s * (1.0f / 192.0f);
    float var = q * (1.0f / 192.0f) - mean * mean;
    float rs = rsqrtf(var + 1e-5f);
    bf16* orow = xw + (size_t)t * CDIM;
    orow[lane]       = f2bf((v0 - mean) * rs * g[lane]       + bta[lane]);
    orow[lane + 64]  = f2bf((v1 - mean) * rs * g[lane + 64]  + bta[lane + 64]);
    orow[lane + 128] = f2bf((v2 - mean) * rs * g[lane + 128] + bta[lane + 128]);
}

// ---------------------------------------------------------------------------
// Weight transpose + fp32->bf16: in[K,N] f32 -> out[N,K] bf16
// ---------------------------------------------------------------------------
__global__ void k_transpose(const float* __restrict__ in, bf16* __restrict__ out, int K, int N) {
    int i = blockIdx.x * 256 + threadIdx.x;
    if (i < K * N) {
        int k = i / N, n = i - k * N;
        out[(size_t)n * K + k] = f2bf(in[i]);
    }
}

// ---------------------------------------------------------------------------
// Dynamic position-bias MLP (all fp32): 225 rows, 3 stages of LN->ReLU->W.
// ---------------------------------------------------------------------------
__global__ __launch_bounds__(256) void k_posmlp(
    const float* __restrict__ pp_w, const float* __restrict__ pp_b,
    const float* __restrict__ p1_g, const float* __restrict__ p1_b,
    const float* __restrict__ p1_w, const float* __restrict__ p1_bias,
    const float* __restrict__ p2_g, const float* __restrict__ p2_b,
    const float* __restrict__ p2_w, const float* __restrict__ p2_bias,
    const float* __restrict__ p3_g, const float* __restrict__ p3_b,
    const float* __restrict__ p3_w, const float* __restrict__ p3_bias,
    float* __restrict__ pos) {
    int i = threadIdx.x;
    if (i >= 225) return;
    float bh = (float)(i / 15 - 7), bw = (float)(i % 15 - 7);
    float v[12], u[12];
#pragma unroll
    for (int j = 0; j < 12; j++)
        v[j] = bh * pp_w[j] + bw * pp_w[12 + j] + pp_b[j];

    auto stage = [&](const float* gg, const float* bb2, const float* Wm, const float* bs, int OD) {
        float mean = 0.f;
        for (int j = 0; j < 12; j++) mean += v[j];
        mean *= (1.0f / 12.0f);
        float var = 0.f;
        for (int j = 0; j < 12; j++) { float d = v[j] - mean; var += d * d; }
        var *= (1.0f / 12.0f);
        float rs = rsqrtf(var + 1e-5f);
        for (int j = 0; j < 12; j++)
            u[j] = fmaxf((v[j] - mean) * rs * gg[j] + bb2[j], 0.0f);
        for (int o = 0; o < OD; o++) {
            float a = bs[o];
            for (int j = 0; j < 12; j++) a += u[j] * Wm[j * OD + o];
            v[o] = a;
        }
    };
    stage(p1_g, p1_b, p1_w, p1_bias, 12);
    stage(p2_g, p2_b, p2_w, p2_bias, 12);
    stage(p3_g, p3_b, p3_w, p3_bias, 6);
    for (int h = 0; h < 6; h++) pos[i * 6 + h] = v[h];
}

// ---------------------------------------------------------------------------
// MFMA GEMM: C[M,N] = act(A[M,K] @ W[K,N] + bias) (+ residual in C)
// A,Bt bf16; bias fp32; OutT = bf16 or float. Tile 128x64, BK=64, 4 waves.
// ---------------------------------------------------------------------------
template <int ACT, int RESID, typename OutT>
__global__ __launch_bounds__(256) void k_gemm(const bf16* __restrict__ A,
                                              const bf16* __restrict__ Bt,
                                              const float* __restrict__ bias,
                                              OutT* __restrict__ Cd,
                                              int M, int N, int K) {
    constexpr int BM = 128, BN = 64, BK = 64, LDT = 72;
    __shared__ __align__(16) unsigned short As[BM * LDT];
    __shared__ __align__(16) unsigned short Bs[BN * LDT];
    int tid = threadIdx.x;
    int wave = tid >> 6, lane = tid & 63;
    int lm = lane & 15, quad = lane >> 4;
    int m0 = blockIdx.x * BM, n0 = blockIdx.y * BN;

    f32x4 acc[2][4] = {};

    for (int k0 = 0; k0 < K; k0 += BK) {
#pragma unroll
        for (int i = 0; i < 4; i++) {
            int c = tid + i * 256;
            int row = c >> 3, col = (c & 7) << 3;
            *(uint4*)&As[row * LDT + col] =
                *(const uint4*)&A[(size_t)(m0 + row) * K + k0 + col];
        }
#pragma unroll
        for (int i = 0; i < 2; i++) {
            int c = tid + i * 256;
            int row = c >> 3, col = (c & 7) << 3;
            *(uint4*)&Bs[row * LDT + col] =
                *(const uint4*)&Bt[(size_t)(n0 + row) * K + k0 + col];
        }
        __syncthreads();
#pragma unroll
        for (int ks = 0; ks < BK; ks += 32) {
            bf16x8 af[2], bfr[4];
#pragma unroll
            for (int im = 0; im < 2; im++)
                af[im] = *(const bf16x8*)&As[(wave * 32 + im * 16 + lm) * LDT + ks + quad * 8];
#pragma unroll
            for (int in = 0; in < 4; in++)
                bfr[in] = *(const bf16x8*)&Bs[(in * 16 + lm) * LDT + ks + quad * 8];
#pragma unroll
            for (int im = 0; im < 2; im++)
#pragma unroll
                for (int in = 0; in < 4; in++)
                    acc[im][in] = __builtin_amdgcn_mfma_f32_16x16x32_bf16(
                        af[im], bfr[in], acc[im][in], 0, 0, 0);
        }
        __syncthreads();
    }

    // epilogue: C/D layout col=lane&15, row=quad*4+reg
#pragma unroll
    for (int im = 0; im < 2; im++) {
        int rbase = m0 + wave * 32 + im * 16 + quad * 4;
#pragma unroll
        for (int in = 0; in < 4; in++) {
            int cg = n0 + in * 16 + lm;
            float bv = bias[cg];
#pragma unroll
            for (int r = 0; r < 4; r++) {
                float v = acc[im][in][r] + bv;
                if (ACT == 1) v = 0.5f * v * (1.0f + erff(v * 0.70710678118654752f));
                size_t o = (size_t)(rbase + r) * N + cg;
                if (RESID) v += (float)Cd[o];
                Cd[o] = (OutT)v;
            }
        }
    }
}

// ---------------------------------------------------------------------------
// MFMA attention: one block per window, 4 waves, 6 heads sequential.
// Per head: S = Q·K^T (4 MFMAs/wave), softmax in C/D-layout registers,
// P -> LDS, PV = P·Vt (4 MFMAs/wave). qkv bf16 in, bf16 out.
// ---------------------------------------------------------------------------
__global__ __launch_bounds__(256) void k_attn(const bf16* __restrict__ qkv,
                                              const float* __restrict__ pos,
                                              bf16* __restrict__ outp) {
    __shared__ __align__(16) unsigned short Qs[64 * 40];  // 32 + 8 pad
    __shared__ __align__(16) unsigned short Ks[64 * 40];
    __shared__ __align__(16) unsigned short Vt[32 * 72];  // transposed: [d][m], 64 + 8 pad
    __shared__ __align__(16) unsigned short Ps[64 * 72];
    int w = blockIdx.x, tid = threadIdx.x;
    int wv = tid >> 6, lane = tid & 63;
    int lm = lane & 15, quad = lane >> 4;
    int wy = (w >> 4) & 15, wx = w & 15;
    bool edge = (wy == 15) || (wx == 15);
    const float scale = 0.17677669529663687f;  // 32^-0.5

    // staging coords: thread covers 8 contiguous bf16 of one row's head-slice
    int srow = tid >> 2, scol = (tid & 3) << 3;
    const unsigned short* gq =
        (const unsigned short*)qkv + ((size_t)w * 64 + srow) * 576 + scol;

    // precompute per-lane score coords (row n varies with quad/r; col m with ct/lm)
    int nbase = wv * 16 + quad * 4;

    for (int h = 0; h < 6; ++h) {
        // ---- stage Q, K, V(transposed) for this head ----
        uint4 uq = *(const uint4*)(gq + h * 32);
        uint4 uk = *(const uint4*)(gq + h * 32 + 192);
        uint4 uv = *(const uint4*)(gq + h * 32 + 384);
        *(uint4*)&Qs[srow * 40 + scol] = uq;
        *(uint4*)&Ks[srow * 40 + scol] = uk;
        const unsigned short* pv = (const unsigned short*)&uv;
#pragma unroll
        for (int j = 0; j < 8; j++) Vt[(scol + j) * 72 + srow] = pv[j];
        __syncthreads();

        // ---- S = Q K^T : wave wv owns query rows [wv*16, wv*16+16) ----
        f32x4 acc[4];
        bf16x8 af = *(const bf16x8*)&Qs[(wv * 16 + lm) * 40 + quad * 8];
#pragma unroll
        for (int ct = 0; ct < 4; ++ct) {
            bf16x8 bfk = *(const bf16x8*)&Ks[(ct * 16 + lm) * 40 + quad * 8];
            f32x4 z = {0.f, 0.f, 0.f, 0.f};
            acc[ct] = __builtin_amdgcn_mfma_f32_16x16x32_bf16(af, bfk, z, 0, 0, 0);
        }

        // ---- + scale + pos bias + shift mask (lane: n=nbase+r, m=ct*16+lm) ----
        float sv[4][4];
#pragma unroll
        for (int ct = 0; ct < 4; ++ct) {
            int m = ct * 16 + lm;
            int iym = m >> 3, ixm = m & 7;
            int hm = wy * 8 + iym, wm = wx * 8 + ixm;
            int ridm = (hm < 120 ? 0 : (hm < 124 ? 1 : 2)) * 3 +
                       (wm < 120 ? 0 : (wm < 124 ? 1 : 2));
#pragma unroll
            for (int r = 0; r < 4; r++) {
                int n = nbase + r;
                int iyn = n >> 3, ixn = n & 7;
                float s = acc[ct][r] * scale +
                          pos[((iyn - iym + 7) * 15 + (ixn - ixm + 7)) * 6 + h];
                if (edge) {
                    int hn = wy * 8 + iyn, wn = wx * 8 + ixn;
                    int ridn = (hn < 120 ? 0 : (hn < 124 ? 1 : 2)) * 3 +
                               (wn < 120 ? 0 : (wn < 124 ? 1 : 2));
                    if (ridn != ridm) s -= 100.0f;
                }
                sv[ct][r] = s;
            }
        }

        // ---- softmax over 64 cols: reduce 4 regs + 16-lane shuffle group ----
#pragma unroll
        for (int r = 0; r < 4; r++) {
            float mx = fmaxf(fmaxf(sv[0][r], sv[1][r]), fmaxf(sv[2][r], sv[3][r]));
#pragma unroll
            for (int o = 1; o < 16; o <<= 1) mx = fmaxf(mx, __shfl_xor(mx, o));
            float e0 = expf(sv[0][r] - mx), e1 = expf(sv[1][r] - mx);
            float e2 = expf(sv[2][r] - mx), e3 = expf(sv[3][r] - mx);
            float sum = e0 + e1 + e2 + e3;
#pragma unroll
            for (int o = 1; o < 16; o <<= 1) sum += __shfl_xor(sum, o);
            float inv = 1.0f / sum;
            int n = nbase + r;
            *(bf16*)&Ps[n * 72 + lm]      = f2bf(e0 * inv);
            *(bf16*)&Ps[n * 72 + 16 + lm] = f2bf(e1 * inv);
            *(bf16*)&Ps[n * 72 + 32 + lm] = f2bf(e2 * inv);
            *(bf16*)&Ps[n * 72 + 48 + lm] = f2bf(e3 * inv);
        }
        __syncthreads();

        // ---- PV: out rows [wv*16,+16), cols d 0..31 (2 tiles), K=64 ----
        f32x4 o0 = {0.f, 0.f, 0.f, 0.f}, o1 = {0.f, 0.f, 0.f, 0.f};
#pragma unroll
        for (int kc = 0; kc < 2; kc++) {
            bf16x8 pa = *(const bf16x8*)&Ps[(wv * 16 + lm) * 72 + kc * 32 + quad * 8];
            bf16x8 vb0 = *(const bf16x8*)&Vt[lm * 72 + kc * 32 + quad * 8];
            bf16x8 vb1 = *(const bf16x8*)&Vt[(16 + lm) * 72 + kc * 32 + quad * 8];
            o0 = __builtin_amdgcn_mfma_f32_16x16x32_bf16(pa, vb0, o0, 0, 0, 0);
            o1 = __builtin_amdgcn_mfma_f32_16x16x32_bf16(pa, vb1, o1, 0, 0, 0);
        }
#pragma unroll
        for (int r = 0; r < 4; r++) {
            int n = nbase + r;
            size_t base = ((size_t)w * 64 + n) * 192 + h * 32;
            outp[base + lm]      = f2bf(o0[r]);
            outp[base + 16 + lm] = f2bf(o1[r]);
        }
        __syncthreads();  // before next head's staging overwrites Q/K/Vt
    }
}

// ---------------------------------------------------------------------------
// K5: window reverse + shift back (+4,+4) + residual -> y (fp32 d_out),
// then LN2(y) -> h2 (bf16).
// ---------------------------------------------------------------------------
__global__ __launch_bounds__(256) void k_resid_ln2(const float* __restrict__ x,
                                                   const bf16* __restrict__ proj,
                                                   const float* __restrict__ g,
                                                   const float* __restrict__ bta,
                                                   float* __restrict__ yout,
                                                   bf16* __restrict__ h2) {
    int tid = threadIdx.x, lane = tid & 63;
    int t = (blockIdx.x << 2) + (tid >> 6);
    int bb = t >> 14, l = t & 16383;
    int h = l >> 7, ww = l & 127;
    int hr = (h + 124) & 127, wr = (ww + 124) & 127;  // (h-4) mod 128
    int win = bb * 256 + (hr >> 3) * 16 + (wr >> 3);
    int n = ((hr & 7) << 3) + (wr & 7);
    const float* xr = x + (size_t)t * CDIM;
    const bf16* pr = proj + ((size_t)win * 64 + n) * CDIM;
    float v0 = nz(xr[lane])       + bf2f(pr[lane]);
    float v1 = nz(xr[lane + 64])  + bf2f(pr[lane + 64]);
    float v2 = nz(xr[lane + 128]) + bf2f(pr[lane + 128]);
    float* yr = yout + (size_t)t * CDIM;
    yr[lane]       = v0;
    yr[lane + 64]  = v1;
    yr[lane + 128] = v2;
    float s = v0 + v1 + v2;
    float q = v0 * v0 + v1 * v1 + v2 * v2;
#pragma unroll
    for (int o = 32; o > 0; o >>= 1) { s += __shfl_xor(s, o); q += __shfl_xor(q, o); }
    float mean = s * (1.0f / 192.0f);
    float var = q * (1.0f / 192.0f) - mean * mean;
    float rs = rsqrtf(var + 1e-5f);
    bf16* hr2 = h2 + (size_t)t * CDIM;
    hr2[lane]       = f2bf((v0 - mean) * rs * g[lane]       + bta[lane]);
    hr2[lane + 64]  = f2bf((v1 - mean) * rs * g[lane + 64]  + bta[lane + 64]);
    hr2[lane + 128] = f2bf((v2 - mean) * rs * g[lane + 128] + bta[lane + 128]);
}

// ---------------------------------------------------------------------------
extern "C" void kernel_launch(void* const* d_in, const int* in_sizes, int n_in,
                              void* d_out, int out_size, void* d_ws, size_t ws_size,
                              hipStream_t stream) {
    (void)in_sizes; (void)n_in; (void)out_size;
    const float* x      = (const float*)d_in[0];
    const float* n1_g   = (const float*)d_in[4];
    const float* n1_b   = (const float*)d_in[5];
    const float* qkv_w  = (const float*)d_in[6];
    const float* qkv_b  = (const float*)d_in[7];
    const float* proj_w = (const float*)d_in[8];
    const float* proj_b = (const float*)d_in[9];
    const float* pp_w   = (const float*)d_in[10];
    const float* pp_b   = (const float*)d_in[11];
    const float* p1_g   = (const float*)d_in[12];
    const float* p1_b   = (const float*)d_in[13];
    const float* p1_w   = (const float*)d_in[14];
    const float* p1_bias= (const float*)d_in[15];
    const float* p2_g   = (const float*)d_in[16];
    const float* p2_b   = (const float*)d_in[17];
    const float* p2_w   = (const float*)d_in[18];
    const float* p2_bias= (const float*)d_in[19];
    const float* p3_g   = (const float*)d_in[20];
    const float* p3_b   = (const float*)d_in[21];
    const float* p3_w   = (const float*)d_in[22];
    const float* p3_bias= (const float*)d_in[23];
    const float* n2_g   = (const float*)d_in[24];
    const float* n2_b   = (const float*)d_in[25];
    const float* fc1_w  = (const float*)d_in[26];
    const float* fc1_b  = (const float*)d_in[27];
    const float* fc2_w  = (const float*)d_in[28];
    const float* fc2_b  = (const float*)d_in[29];

    char* ws = (char*)d_ws;
    size_t off = 0;
    auto alloc = [&](size_t bytes) -> char* {
        char* p = ws + off;
        off += (bytes + 255) & ~(size_t)255;
        return p;
    };
    // bf16 weight copies + pos (~0.9 MB)
    bf16* qkvwT  = (bf16*)alloc((size_t)CDIM * 576 * 2);
    bf16* projwT = (bf16*)alloc((size_t)CDIM * CDIM * 2);
    bf16* fc1wT  = (bf16*)alloc((size_t)CDIM * HIDDEN * 2);
    bf16* fc2wT  = (bf16*)alloc((size_t)HIDDEN * CDIM * 2);
    float* pos   = (float*)alloc(225 * 6 * 4);

    const size_t flatNeed = (size_t)ROWS * CDIM * 2 + (size_t)ROWS * HIDDEN * 2 + (1u << 20);
    const bool flat = (ws_size > off) && ((ws_size - off) >= flatNeed);
    const int NCH = flat ? 1 : 8;
    const int NIMG = flat ? 8 : 1;
    const size_t R = (size_t)16384 * NIMG;   // rows per chunk

    bf16 *xw_b, *qkv_buf, *attn_b, *proj_buf, *h2_b, *fc1_buf;
    if (flat) {
        bf16* region0 = (bf16*)alloc((size_t)ROWS * CDIM * 2);
        bf16* region1 = (bf16*)alloc((size_t)ROWS * HIDDEN * 2);
        xw_b = attn_b = h2_b = region0;            // sequential lifetimes
        qkv_buf  = region1;
        proj_buf = region1 + (size_t)ROWS * 576;
        fc1_buf  = region1;                        // qkv/proj dead by then
    } else {
        xw_b     = (bf16*)alloc(R * CDIM * 2);
        qkv_buf  = (bf16*)alloc(R * 576 * 2);
        attn_b   = (bf16*)alloc(R * CDIM * 2);
        proj_buf = (bf16*)alloc(R * CDIM * 2);
        h2_b     = (bf16*)alloc(R * CDIM * 2);
        fc1_buf  = (bf16*)alloc(R * HIDDEN * 2);
    }
    float* yout = (float*)d_out;

    // prep (tiny)
    k_transpose<<<(CDIM * 576 + 255) / 256, 256, 0, stream>>>(qkv_w, qkvwT, CDIM, 576);
    k_transpose<<<(CDIM * CDIM + 255) / 256, 256, 0, stream>>>(proj_w, projwT, CDIM, CDIM);
    k_transpose<<<(CDIM * HIDDEN + 255) / 256, 256, 0, stream>>>(fc1_w, fc1wT, CDIM, HIDDEN);
    k_transpose<<<(HIDDEN * CDIM + 255) / 256, 256, 0, stream>>>(fc2_w, fc2wT, HIDDEN, CDIM);
    k_posmlp<<<1, 256, 0, stream>>>(pp_w, pp_b, p1_g, p1_b, p1_w, p1_bias,
                                    p2_g, p2_b, p2_w, p2_bias,
                                    p3_g, p3_b, p3_w, p3_bias, pos);

    for (int c = 0; c < NCH; ++c) {
        const float* x_c = x + (size_t)c * 16384 * CDIM;
        float* y_c = yout + (size_t)c * 16384 * CDIM;

        k_ln1_part<<<(int)(R / 4), 256, 0, stream>>>(x_c, n1_g, n1_b, xw_b);

        k_gemm<0, 0, bf16><<<dim3((int)(R / 128), 576 / 64), 256, 0, stream>>>(
            xw_b, qkvwT, qkv_b, qkv_buf, (int)R, 576, CDIM);

        k_attn<<<(int)(R / 64), 256, 0, stream>>>(qkv_buf, pos, attn_b);

        k_gemm<0, 0, bf16><<<dim3((int)(R / 128), CDIM / 64), 256, 0, stream>>>(
            attn_b, projwT, proj_b, proj_buf, (int)R, CDIM, CDIM);

        k_resid_ln2<<<(int)(R / 4), 256, 0, stream>>>(x_c, proj_buf, n2_g, n2_b, y_c, h2_b);

        k_gemm<1, 0, bf16><<<dim3((int)(R / 128), HIDDEN / 64), 256, 0, stream>>>(
            h2_b, fc1wT, fc1_b, fc1_buf, (int)R, HIDDEN, CDIM);

        k_gemm<0, 1, float><<<dim3((int)(R / 128), CDIM / 64), 256, 0, stream>>>(
            fc1_buf, fc2wT, fc2_b, y_c, (int)R, CDIM, HIDDEN);
    }
}